// Round 16
// baseline (4660.225 us; speedup 1.0000x reference)
//
#include <hip/hip_runtime.h>
#include <cstdint>
#include <cstddef>

// Problem constants (fixed by the reference)
#define T_STEPS 256
#define BATCH   256
#define DIN     512
#define HID     1024
#define KTOT    1536   // DIN + HID
#define NOUT    4096   // 4*HID
#define BHSZ    ((size_t)BATCH * HID)   // 262144 elems

typedef __bf16 bf16;
typedef __bf16 bf16x4 __attribute__((ext_vector_type(4)));
typedef __bf16 bf16x8 __attribute__((ext_vector_type(8)));
typedef float  f32x4  __attribute__((ext_vector_type(4)));

// cross-XCD-visible bf16 store (write-through to MALL)
__device__ __forceinline__ void store_bf16_sc(bf16* p, bf16 v) {
  unsigned short u = __builtin_bit_cast(unsigned short, v);
  asm volatile("global_store_short %0, %1, off sc0 sc1" :: "v"(p), "v"(u) : "memory");
}

// counted vmcnt wait + scheduler fence (rule #18)
#define VMW_(N) asm volatile("s_waitcnt vmcnt(" #N ")" ::: "memory")
#define VMW(N) do { VMW_(N); __builtin_amdgcn_sched_barrier(0); } while (0)
#define LGKM0() do { asm volatile("s_waitcnt lgkmcnt(0)" ::: "memory"); \
                     __builtin_amdgcn_sched_barrier(0); } while (0)
#define SBAR() __builtin_amdgcn_sched_barrier(0)
// raw workgroup barrier: NO implicit vmcnt(0) drain (unlike __syncthreads)
#define RAWBAR() do { SBAR(); __builtin_amdgcn_s_barrier(); SBAR(); } while (0)

// fast transcendentals (bf16-tolerance OK; saturation-correct)
__device__ __forceinline__ float fexp2(float x) {
  float r; asm("v_exp_f32 %0, %1" : "=v"(r) : "v"(x)); return r;
}
__device__ __forceinline__ float frcp(float x) {
  float r; asm("v_rcp_f32 %0, %1" : "=v"(r) : "v"(x)); return r;
}
__device__ __forceinline__ float fsigmoid(float x) {
  return frcp(1.f + fexp2(-1.44269504f * x));
}
__device__ __forceinline__ float ftanh(float x) {
  return 1.f - 2.f * frcp(1.f + fexp2(2.88539008f * x));
}

// ---------------------------------------------------------------------------
// Gate-interleaved transposed weights: Wt[(j>>4)*64 + gate*16 + (j&15)][k]
__global__ void convert_w_kernel(const float* __restrict__ Wf, const float* __restrict__ Wi,
                                 const float* __restrict__ Wg, const float* __restrict__ Wo,
                                 bf16* __restrict__ Wt) {
  __shared__ float tile[64][17];
  const int k0 = blockIdx.x * 64;
  const int jb = blockIdx.y;
  const int j0 = jb * 16;
  const int t  = threadIdx.x;
  const float* srcs[4] = {Wf, Wi, Wg, Wo};
#pragma unroll
  for (int g = 0; g < 4; ++g) {
    const float* src = srcs[g];
    {
      const int jl = t & 15, kb = t >> 4;
#pragma unroll
      for (int r = 0; r < 4; ++r) {
        const int kl = kb + 16 * r;
        tile[kl][jl] = src[(size_t)(k0 + kl) * HID + (j0 + jl)];
      }
    }
    __syncthreads();
    {
      const int kk = t & 63, jl4 = t >> 6;
#pragma unroll
      for (int r = 0; r < 4; ++r) {
        const int jl = jl4 + 4 * r;
        Wt[(size_t)(jb * 64 + g * 16 + jl) * KTOT + (k0 + kk)] = (bf16)tile[kk][jl];
      }
    }
    __syncthreads();
  }
}

// fp32 -> bf16 convert of X (big-ws path)
__global__ void convert_x_kernel(const float* __restrict__ X, bf16* __restrict__ xb) {
  const int t = blockIdx.y;
  const int i = blockIdx.x * blockDim.x + threadIdx.x;
  const float4 v = ((const float4*)(X + (size_t)t * BATCH * DIN))[i];
  bf16x4 o;
  o[0] = (bf16)v.x; o[1] = (bf16)v.y; o[2] = (bf16)v.z; o[3] = (bf16)v.w;
  ((bf16x4*)(xb + (size_t)t * BATCH * DIN))[i] = o;
}

// ---------------------------------------------------------------------------
// Persistent LSTM v15 = v13 + next-step x-MFMA prefill in the hA RTT window.
// Two acc generations (cur has x(t) prefilled; next gets x(t+1) during t).
// Queue ledger (steady, per wave):
//  entry [x'(t+1) 8]
//  pollA ; ldhA(8) -> 16
//  VMW(12): xA' -> MFMA accNextA ; VMW(8): xB' -> MFMA accNextB   (covers hA)
//  pollB ; ldhB(8 into freed x slots) -> 16
//  VMW(14/12/10/8): hA ladder -> accCurA
//  dumpA ; RAWBAR ; finishA (stores stA2) -> [hB8, stA2]
//  VMW(8): hB s2 ; RAWBAR(WAR) ; VMW(6/4/2): hB ladder -> accCurB
//  dumpB ; RAWBAR ; finishB (stB2) ; ldx(t+2 into x slots)(8)
//  VMW(10): stA acked -> flagA ; VMW(8): stB acked -> flagB ; RAWBAR
// Flags publish at the same point as v13 (r14 lesson: never delay flags).
__global__ __launch_bounds__(512, 2)
void lstm_v15(const bf16* __restrict__ Bt,
              const bf16* __restrict__ xb,
              bf16* __restrict__ hseq,
              const bf16* __restrict__ zb16,     // >= 1MB zeros
              float* __restrict__ outF,
              const float* __restrict__ bf_, const float* __restrict__ bi_,
              const float* __restrict__ bg_, const float* __restrict__ bo_,
              unsigned* __restrict__ flags) {    // [T][2][256], zeroed
  __shared__ f32x4 redu[8][8][64];   // 64 KiB, reused A/B with barriers

  const int tid = threadIdx.x, lane = tid & 63, wid = tid >> 6;
  const int bid = blockIdx.x;
  const int e8  = bid & 7;
  const int mh   = e8 >> 1;                      // row-group (32 rows/half)
  const int nblk = ((bid >> 3) << 1) | (e8 & 1); // bijective 0..63
  const int bn0 = nblk * 64;
  const int fr = lane & 15, fq = lane >> 4;
  const int rowA = mh * 32, rowB = 128 + mh * 32;

  // once-per-launch agent acquire: invalidate stale L2 lines (graph replays)
  if (tid == 0)
    (void)__hip_atomic_load(flags, __ATOMIC_ACQUIRE, __HIP_MEMORY_SCOPE_AGENT);
  __syncthreads();

  const int j = nblk * 16 + fr;
  const float bfv = bf_[j], biv = bi_[j], bgv = bg_[j], bov = bo_[j];
  float crA = 0.f, crB = 0.f;      // 1 cell per thread per half

  // ---- B panel -> registers, once (96 VGPR/lane), shared by both halves
  bf16x8 breg[6][4];
#pragma unroll
  for (int s = 0; s < 6; ++s) {
    const int ks = wid + 8 * s;
#pragma unroll
    for (int nf = 0; nf < 4; ++nf)
      breg[s][nf] = *(const bf16x8*)(Bt + (size_t)(bn0 + nf * 16 + fr) * KTOT
                                     + ks * 32 + fq * 8);
  }

  // slots: X0..X3 dual-use (x(t+1) then hB), H2..H5 for hA
  bf16x8 X0[2], X1[2], X2[2], X3[2], H2[2], H3[2], H4[2], H5[2];
  // two accumulator generations
  f32x4 aA0[2][4], aB0[2][4], aA1[2][4], aB1[2][4];

  auto ldx = [&](int t2, int rowbase, int s, bf16x8 (&sl)[2]) {
    const bf16* src = xb + (size_t)t2 * BATCH * DIN + (wid + 8 * s) * 32 + fq * 8;
#pragma unroll
    for (int mf = 0; mf < 2; ++mf)
      sl[mf] = *(const bf16x8*)(src + (size_t)(rowbase + mf * 16 + fr) * DIN);
  };
  auto ldh = [&](int t2, int half, int s, bf16x8 (&sl)[2]) {
    const int c0 = (wid + 8 * s) * 32 - 512;
    const int pp = (c0 >> 4) + (fq >> 1);
    const bf16* base = (t2 == 0)
        ? zb16
        : hseq + ((((size_t)(t2 - 1) * 2 + half) << 8) + mh * 64 + pp) * 512;
    const int coloff = (fq & 1) * 8;
#pragma unroll
    for (int mf = 0; mf < 2; ++mf)
      sl[mf] = *(const bf16x8*)(base + (mf * 16 + fr) * 16 + coloff);
  };

  // per-wave poll of this wave's 8 h-producers (same (half, mh) group)
  const int pn8 = 2 * wid + ((lane & 7) >> 1) * 16 + (lane & 1);
  auto pollh = [&](int tprev, int half) {
    const unsigned* f = flags + (((size_t)tprev * 2 + half) << 8) + mh * 64 + pn8;
    const unsigned long long tt0 = __builtin_amdgcn_s_memrealtime();
    for (;;) {
      unsigned v = __hip_atomic_load(f, __ATOMIC_RELAXED,
                                     __HIP_MEMORY_SCOPE_AGENT);
      if (__all(v != 0)) break;
      __builtin_amdgcn_s_sleep(1);
      if (__builtin_amdgcn_s_memrealtime() - tt0 > (1ULL << 22)) break;  // fail-soft
    }
    asm volatile("" ::: "memory");
    __builtin_amdgcn_sched_barrier(0);
  };

  auto dump = [&](f32x4 (&acc)[2][4]) {
#pragma unroll
    for (int mf = 0; mf < 2; ++mf)
#pragma unroll
      for (int nf = 0; nf < 4; ++nf)
        redu[wid][mf * 4 + nf][lane] = acc[mf][nf];
  };

  // owner cell: row = wid*4+fq (of 32), col j  (v13-verified)
  auto finish = [&](int t2, int half, float& cre) {
    const int mf_c = wid >> 2;
    const int lsel = (wid & 3) * 16 + fr;
    float z[4];
#pragma unroll
    for (int nf = 0; nf < 4; ++nf) {
      float s_ = 0.f;
#pragma unroll
      for (int s = 0; s < 8; ++s)
        s_ += ((const float*)&redu[s][mf_c * 4 + nf][lsel])[fq];
      z[nf] = s_;
    }
    const float fg = fsigmoid(z[0] + bfv);
    const float ig = fsigmoid(z[1] + biv);
    const float gg = ftanh(z[2] + bgv);
    const float og = fsigmoid(z[3] + bov);
    cre = fg * cre + ig * gg;
    const float h = og * ftanh(cre);
    bf16* tile = hseq + ((((size_t)t2 * 2 + half) << 8) + mh * 64 + nblk) * 512;
    store_bf16_sc(&tile[wid * 64 + lane], (bf16)h);     // one full 128B line
    const int rowg = half * 128 + mh * 32 + wid * 4 + fq;
    outF[(size_t)t2 * BHSZ + (size_t)rowg * HID + j] = h;
    if (t2 == T_STEPS - 1)
      outF[(size_t)(T_STEPS + 1) * BHSZ + (size_t)rowg * HID + j] = cre;
  };

  auto setflag = [&](int t2, int half) {
    __hip_atomic_store(&flags[(((size_t)t2 * 2 + half) << 8) + mh * 64 + nblk],
                       1u, __ATOMIC_RELAXED, __HIP_MEMORY_SCOPE_AGENT);
  };

#define MFMA8(ACC, SL, S) do {                                              \
    __builtin_amdgcn_s_setprio(1);                                          \
    _Pragma("unroll")                                                       \
    for (int mf_ = 0; mf_ < 2; ++mf_) {                                     \
      _Pragma("unroll")                                                     \
      for (int nf_ = 0; nf_ < 4; ++nf_)                                     \
        ACC[mf_][nf_] = __builtin_amdgcn_mfma_f32_16x16x32_bf16(            \
            SL[mf_], breg[S][nf_], ACC[mf_][nf_], 0, 0, 0);                 \
    }                                                                       \
    __builtin_amdgcn_s_setprio(0);                                          \
  } while (0)

#define ZERO8(ACC) do {                                                     \
    _Pragma("unroll")                                                       \
    for (int mf_ = 0; mf_ < 2; ++mf_) {                                     \
      _Pragma("unroll")                                                     \
      for (int nf_ = 0; nf_ < 4; ++nf_)                                     \
        ACC[mf_][nf_] = (f32x4){0.f, 0.f, 0.f, 0.f};                        \
    }                                                                       \
  } while (0)

#define STEP(T0, CA, CB, NA, NB) do {                                       \
    const int t_ = (T0);                                                    \
    const bool hasNext = (t_ + 1 < T_STEPS);                                \
    const bool hasNext2 = (t_ + 2 < T_STEPS);                               \
    if (hasNext) { ZERO8(NA); ZERO8(NB); }                                  \
    if (t_ > 0) pollh(t_ - 1, 0);                                           \
    ldh(t_, 0, 2, H2); ldh(t_, 0, 3, H3);                                   \
    ldh(t_, 0, 4, H4); ldh(t_, 0, 5, H5); SBAR();                           \
    if (hasNext) {                                                          \
      VMW(12); MFMA8(NA, X0, 0); MFMA8(NA, X1, 1);   /* x(t+1) half A */    \
      VMW(8);  MFMA8(NB, X2, 0); MFMA8(NB, X3, 1);   /* x(t+1) half B */    \
    }                                                                       \
    if (t_ > 0) pollh(t_ - 1, 1);                                           \
    ldh(t_, 1, 2, X0); ldh(t_, 1, 3, X1);                                   \
    ldh(t_, 1, 4, X2); ldh(t_, 1, 5, X3); SBAR();                           \
    VMW(14); MFMA8(CA, H2, 2);                                              \
    VMW(12); MFMA8(CA, H3, 3);                                              \
    VMW(10); MFMA8(CA, H4, 4);                                              \
    VMW(8);  MFMA8(CA, H5, 5);                                              \
    dump(CA); LGKM0(); RAWBAR();                                            \
    finish(t_, 0, crA);                     /* stores stA */                \
    VMW(8);                                 /* hB s2 landed */              \
    RAWBAR();        /* WAR: reduceA reads before dumpB writes */           \
    MFMA8(CB, X0, 2);                                                       \
    VMW(6); MFMA8(CB, X1, 3);                                               \
    VMW(4); MFMA8(CB, X2, 4);                                               \
    VMW(2); MFMA8(CB, X3, 5);                                               \
    dump(CB); LGKM0(); RAWBAR();                                            \
    finish(t_, 1, crB);                     /* stores stB */                \
    if (hasNext2) {                                                         \
      ldx(t_ + 2, rowA, 0, X0); ldx(t_ + 2, rowA, 1, X1);                   \
      ldx(t_ + 2, rowB, 0, X2); ldx(t_ + 2, rowB, 1, X3); SBAR();           \
      VMW(10);       /* [stA2,stB2,x''8]=12 -> stA acked */                 \
      if (tid == 0) setflag(t_, 0);                                         \
      VMW(8);        /* stB acked; x'' stays in flight */                   \
      if (tid == 0) setflag(t_, 1);                                         \
    } else if (t_ == T_STEPS - 1) {                                         \
      VMW(3);        /* [stA3,stB3]=6 -> stA acked (incl cx) */             \
      if (tid == 0) setflag(t_, 0);                                         \
      VMW(0);                                                               \
      if (tid == 0) setflag(t_, 1);                                         \
    } else {                                                                \
      VMW(2);        /* t=254: [stA2,stB2]=4 -> stA acked */                \
      if (tid == 0) setflag(t_, 0);                                         \
      VMW(0);                                                               \
      if (tid == 0) setflag(t_, 1);                                         \
    }                                                                       \
    RAWBAR();        /* WAR: reduceB reads before next dumpA */             \
  } while (0)

  // prologue: x(0) loaded+consumed into gen0; x(1) left in flight
  ldx(0, rowA, 0, X0); SBAR(); ldx(0, rowA, 1, X1); SBAR();
  ldx(0, rowB, 0, X2); SBAR(); ldx(0, rowB, 1, X3); SBAR();
  ZERO8(aA0); ZERO8(aB0);
  VMW(4); MFMA8(aA0, X0, 0); MFMA8(aA0, X1, 1);
  VMW(0); MFMA8(aB0, X2, 0); MFMA8(aB0, X3, 1);
  ldx(1, rowA, 0, X0); SBAR(); ldx(1, rowA, 1, X1); SBAR();
  ldx(1, rowB, 0, X2); SBAR(); ldx(1, rowB, 1, X3); SBAR();
  // queue: [x(1) 8]

#pragma unroll 1
  for (int t = 0; t < T_STEPS; t += 2) {
    STEP(t,     aA0, aB0, aA1, aB1);
    STEP(t + 1, aA1, aB1, aA0, aB0);
  }
#undef STEP
#undef ZERO8
#undef MFMA8
}

// ---------------------------------------------------------------------------
// Fallback (small ws): round-5 MODE-1 path verbatim (fp32 A from X / out).
__global__ __launch_bounds__(512, 2)
void lstm_fb(const bf16* __restrict__ Bt,
             const float* __restrict__ X,
             const float* __restrict__ zbF,
             float* __restrict__ outF,
             const float* __restrict__ bf_, const float* __restrict__ bi_,
             const float* __restrict__ bg_, const float* __restrict__ bo_,
             unsigned* __restrict__ flags) {
  __shared__ f32x4 redu[8][16][64];
  const int tid = threadIdx.x, lane = tid & 63, wid = tid >> 6;
  const int bid = blockIdx.x;
  const int xcd = bid & 7, sl = bid >> 3;
  const int nblk = xcd * 8 + (sl & 7);
  const int mblk = sl >> 3;
  const int bm0 = mblk * 64;
  const int bn0 = nblk * 64;
  const int fr = lane & 15, fq = lane >> 4;

  if (tid == 0)
    (void)__hip_atomic_load(flags, __ATOMIC_ACQUIRE, __HIP_MEMORY_SCOPE_AGENT);
  __syncthreads();

  const int j = nblk * 16 + fr;
  const float bfv = bf_[j], biv = bi_[j], bgv = bg_[j], bov = bo_[j];
  float cr[2] = {0.f, 0.f};

  bf16x8 breg[6][4];
#pragma unroll
  for (int s = 0; s < 6; ++s) {
    const int ks = wid + 8 * s;
#pragma unroll
    for (int nf = 0; nf < 4; ++nf)
      breg[s][nf] = *(const bf16x8*)(Bt + (size_t)(bn0 + nf * 16 + fr) * KTOT
                                     + ks * 32 + fq * 8);
  }

  bf16x8 afp[2][4];

  auto poll = [&](int tprev) {
    const unsigned* f = flags + (size_t)tprev * 256 + mblk * 64;
    const unsigned long long tt0 = __builtin_amdgcn_s_memrealtime();
    for (;;) {
      unsigned v = __hip_atomic_load(f + lane, __ATOMIC_RELAXED,
                                     __HIP_MEMORY_SCOPE_AGENT);
      if (__all(v != 0)) break;
      __builtin_amdgcn_s_sleep(2);
      if (__builtin_amdgcn_s_memrealtime() - tt0 > (1ULL << 22)) break;
    }
    asm volatile("" ::: "memory");
    __builtin_amdgcn_sched_barrier(0);
  };

  auto loadA = [&](int t2, int s, int p) __attribute__((always_inline)) {
    const int ks = wid + 8 * s;
    const int k = ks * 32 + fq * 8;
    if (s == 2 && t2 > 0) poll(t2 - 1);
    const float* src; int ld, kk;
    if (s < 2) { src = X + (size_t)t2 * BATCH * DIN; ld = DIN; kk = k; }
    else {
      src = (t2 == 0) ? zbF : outF + (size_t)(t2 - 1) * BHSZ;
      ld = HID; kk = k - 512;
    }
#pragma unroll
    for (int mf = 0; mf < 4; ++mf) {
      const float* q = src + (size_t)(bm0 + mf * 16 + fr) * ld + kk;
      const f32x4 lo = *(const f32x4*)q;
      const f32x4 hi = *(const f32x4*)(q + 4);
      bf16x8 v;
      v[0] = (bf16)lo[0]; v[1] = (bf16)lo[1]; v[2] = (bf16)lo[2]; v[3] = (bf16)lo[3];
      v[4] = (bf16)hi[0]; v[5] = (bf16)hi[1]; v[6] = (bf16)hi[2]; v[7] = (bf16)hi[3];
      afp[p][mf] = v;
    }
  };

  loadA(0, 0, 0);

#pragma unroll 1
  for (int t = 0; t < T_STEPS; ++t) {
    f32x4 acc[4][4] = {};
#pragma unroll
    for (int s = 0; s < 6; ++s) {
      if (s < 5)                loadA(t, s + 1, (s + 1) & 1);
      else if (t + 1 < T_STEPS) loadA(t + 1, 0, 0);
      __builtin_amdgcn_s_setprio(1);
#pragma unroll
      for (int mf = 0; mf < 4; ++mf)
#pragma unroll
        for (int nf = 0; nf < 4; ++nf)
          acc[mf][nf] = __builtin_amdgcn_mfma_f32_16x16x32_bf16(
              afp[s & 1][mf], breg[s][nf], acc[mf][nf], 0, 0, 0);
      __builtin_amdgcn_s_setprio(0);
    }

#pragma unroll
    for (int mf = 0; mf < 4; ++mf)
#pragma unroll
      for (int nf = 0; nf < 4; ++nf)
        redu[wid][mf * 4 + nf][lane] = acc[mf][nf];
    __syncthreads();

    const int fbase = (wid >> 1) * 4;
    const int rh = wid & 1;
    float z[2][4];
#pragma unroll
    for (int e = 0; e < 2; ++e) {
      const int rloc = rh * 8 + fq * 2 + e;
      const int lsel = (rloc >> 2) * 16 + fr;
      const int rc = rloc & 3;
#pragma unroll
      for (int nf = 0; nf < 4; ++nf) {
        float sum = 0.f;
#pragma unroll
        for (int s = 0; s < 8; ++s)
          sum += ((const float*)&redu[s][fbase + nf][lsel])[rc];
        z[e][nf] = sum;
      }
    }

    float* outSl = outF + (size_t)t * BHSZ;
#pragma unroll
    for (int e = 0; e < 2; ++e) {
      const float fg = 1.f / (1.f + expf(-(z[e][0] + bfv)));
      const float ig = 1.f / (1.f + expf(-(z[e][1] + biv)));
      const float gg = tanhf(z[e][2] + bgv);
      const float og = 1.f / (1.f + expf(-(z[e][3] + bov)));
      cr[e] = fg * cr[e] + ig * gg;
      const float h = og * tanhf(cr[e]);
      const int m = bm0 + wid * 8 + fq * 2 + e;
      const size_t off = (size_t)m * HID + j;
      __hip_atomic_store(&outSl[off], h, __ATOMIC_RELAXED,
                         __HIP_MEMORY_SCOPE_AGENT);
      if (t == T_STEPS - 1)
        outF[(size_t)(T_STEPS + 1) * BHSZ + off] = cr[e];
    }
    asm volatile("s_waitcnt vmcnt(0)" ::: "memory");
    __syncthreads();
    if (tid == 0)
      __hip_atomic_store(&flags[(size_t)t * 256 + mblk * 64 + nblk], 1u,
                         __ATOMIC_RELAXED, __HIP_MEMORY_SCOPE_AGENT);
  }
}

// ---------------------------------------------------------------------------
extern "C" void kernel_launch(void* const* d_in, const int* in_sizes, int n_in,
                              void* d_out, int out_size, void* d_ws, size_t ws_size,
                              hipStream_t stream) {
  const float* X   = (const float*)d_in[0];
  const float* Wf  = (const float*)d_in[1];
  const float* bf_ = (const float*)d_in[2];
  const float* Wi  = (const float*)d_in[3];
  const float* bi_ = (const float*)d_in[4];
  const float* Wg  = (const float*)d_in[5];
  const float* bg_ = (const float*)d_in[6];
  const float* Wo  = (const float*)d_in[7];
  const float* bo_ = (const float*)d_in[8];
  float* out = (float*)d_out;

  const size_t WtB   = (size_t)NOUT * KTOT * 2;            // 12.58 MB
  const size_t zBb   = BHSZ * 4;                           // 1 MB zeros
  const size_t flagB = (size_t)T_STEPS * 2 * 256 * 4;      // 512 KB
  const size_t XbB   = (size_t)T_STEPS * BATCH * DIN * 2;  // 67.1 MB
  const size_t HsB   = (size_t)T_STEPS * 2 * 256 * 1024;   // 134.2 MB (tiled)

  char* ws = (char*)d_ws;
  bf16*     Wt    = (bf16*)ws;              ws += WtB;
  float*    zbF   = (float*)(void*)ws;      ws += zBb;
  unsigned* flags = (unsigned*)(void*)ws;   ws += flagB;

  const bool big = ws_size >= WtB + zBb + flagB + XbB + HsB + (1u << 20);
  bf16* xbp = nullptr;  bf16* hseq = nullptr;
  if (big) {
    xbp  = (bf16*)ws;   ws += XbB;
    hseq = (bf16*)ws;
  }

  // zeros + flags (re-zeroed every launch -> deterministic)
  hipMemsetAsync(zbF, 0, zBb + flagB, stream);

  convert_w_kernel<<<dim3(KTOT / 64, NOUT / 64), 256, 0, stream>>>(Wf, Wi, Wg, Wo, Wt);

  if (big) {
    convert_x_kernel<<<dim3(BATCH * DIN / 4 / 256, T_STEPS), 256, 0, stream>>>(X, xbp);
    lstm_v15<<<256, 512, 0, stream>>>(Wt, xbp, hseq, (const bf16*)zbF, out,
                                      bf_, bi_, bg_, bo_, flags);
  } else {
    lstm_fb<<<256, 512, 0, stream>>>(Wt, X, zbF, out,
                                     bf_, bi_, bg_, bo_, flags);
  }

  // hx = outputs[T-1] (cx stored by the kernel)
  hipMemcpyAsync(out + (size_t)T_STEPS * BHSZ, out + (size_t)(T_STEPS - 1) * BHSZ,
                 BHSZ * 4, hipMemcpyDeviceToDevice, stream);
}

// Round 17
// 1904.904 us; speedup vs baseline: 2.4464x; 2.4464x over previous
//
#include <hip/hip_runtime.h>
#include <cstdint>
#include <cstddef>

// Problem constants (fixed by the reference)
#define T_STEPS 256
#define BATCH   256
#define DIN     512
#define HID     1024
#define KTOT    1536   // DIN + HID
#define NOUT    4096   // 4*HID
#define BHSZ    ((size_t)BATCH * HID)   // 262144 elems

typedef __bf16 bf16;
typedef __bf16 bf16x4 __attribute__((ext_vector_type(4)));
typedef __bf16 bf16x8 __attribute__((ext_vector_type(8)));
typedef float  f32x4  __attribute__((ext_vector_type(4)));

// cross-XCD-visible bf16 store (write-through to MALL)
__device__ __forceinline__ void store_bf16_sc(bf16* p, bf16 v) {
  unsigned short u = __builtin_bit_cast(unsigned short, v);
  asm volatile("global_store_short %0, %1, off sc0 sc1" :: "v"(p), "v"(u) : "memory");
}

// counted vmcnt wait + scheduler fence (rule #18)
#define VMW_(N) asm volatile("s_waitcnt vmcnt(" #N ")" ::: "memory")
#define VMW(N) do { VMW_(N); __builtin_amdgcn_sched_barrier(0); } while (0)
#define LGKM0() do { asm volatile("s_waitcnt lgkmcnt(0)" ::: "memory"); \
                     __builtin_amdgcn_sched_barrier(0); } while (0)
#define SBAR() __builtin_amdgcn_sched_barrier(0)
// raw workgroup barrier: NO implicit vmcnt(0) drain (unlike __syncthreads)
#define RAWBAR() do { SBAR(); __builtin_amdgcn_s_barrier(); SBAR(); } while (0)

// fast transcendentals (bf16-tolerance OK; saturation-correct)
__device__ __forceinline__ float fexp2(float x) {
  float r; asm("v_exp_f32 %0, %1" : "=v"(r) : "v"(x)); return r;
}
__device__ __forceinline__ float frcp(float x) {
  float r; asm("v_rcp_f32 %0, %1" : "=v"(r) : "v"(x)); return r;
}
__device__ __forceinline__ float fsigmoid(float x) {
  return frcp(1.f + fexp2(-1.44269504f * x));
}
__device__ __forceinline__ float ftanh(float x) {
  return 1.f - 2.f * frcp(1.f + fexp2(2.88539008f * x));
}

// ---------------------------------------------------------------------------
// Gate-interleaved transposed weights: Wt[(j>>4)*64 + gate*16 + (j&15)][k]
__global__ void convert_w_kernel(const float* __restrict__ Wf, const float* __restrict__ Wi,
                                 const float* __restrict__ Wg, const float* __restrict__ Wo,
                                 bf16* __restrict__ Wt) {
  __shared__ float tile[64][17];
  const int k0 = blockIdx.x * 64;
  const int jb = blockIdx.y;
  const int j0 = jb * 16;
  const int t  = threadIdx.x;
  const float* srcs[4] = {Wf, Wi, Wg, Wo};
#pragma unroll
  for (int g = 0; g < 4; ++g) {
    const float* src = srcs[g];
    {
      const int jl = t & 15, kb = t >> 4;
#pragma unroll
      for (int r = 0; r < 4; ++r) {
        const int kl = kb + 16 * r;
        tile[kl][jl] = src[(size_t)(k0 + kl) * HID + (j0 + jl)];
      }
    }
    __syncthreads();
    {
      const int kk = t & 63, jl4 = t >> 6;
#pragma unroll
      for (int r = 0; r < 4; ++r) {
        const int jl = jl4 + 4 * r;
        Wt[(size_t)(jb * 64 + g * 16 + jl) * KTOT + (k0 + kk)] = (bf16)tile[kk][jl];
      }
    }
    __syncthreads();
  }
}

// fp32 -> bf16 convert of X (big-ws path)
__global__ void convert_x_kernel(const float* __restrict__ X, bf16* __restrict__ xb) {
  const int t = blockIdx.y;
  const int i = blockIdx.x * blockDim.x + threadIdx.x;
  const float4 v = ((const float4*)(X + (size_t)t * BATCH * DIN))[i];
  bf16x4 o;
  o[0] = (bf16)v.x; o[1] = (bf16)v.y; o[2] = (bf16)v.z; o[3] = (bf16)v.w;
  ((bf16x4*)(xb + (size_t)t * BATCH * DIN))[i] = o;
}

// ---------------------------------------------------------------------------
// Persistent LSTM v13 (best: 1902us, round 13) — reinstated verbatim.
// Two independent batch halves (rows 0-127 / 128-255) interleaved in every
// block so each half's handoff RTT hides under the other half's compute.
// Block: 32 rows x 64 Wt-rows PER HALF; 8 waves, K-eighth split (6 slices
// of 32k), shared breg (96 VGPR); acc 2x4 frags per half.
// hseq tiles 1KB (32 rows x 16 j); store = one full 128B line per wave.
// Flags per (t, half, block); per-wave 8-producer poll; flags publish at
// the earliest protocol-correct point (r14/r15 lesson: never delay flags).
__global__ __launch_bounds__(512, 2)
void lstm_v13(const bf16* __restrict__ Bt,
              const bf16* __restrict__ xb,
              bf16* __restrict__ hseq,
              const bf16* __restrict__ zb16,     // >= 1KB zeros
              float* __restrict__ outF,
              const float* __restrict__ bf_, const float* __restrict__ bi_,
              const float* __restrict__ bg_, const float* __restrict__ bo_,
              unsigned* __restrict__ flags) {    // [T][2][256], zeroed
  __shared__ f32x4 redu[8][8][64];   // 64 KiB, reused A/B with barriers

  const int tid = threadIdx.x, lane = tid & 63, wid = tid >> 6;
  const int bid = blockIdx.x;
  const int e8  = bid & 7;
  const int mh   = e8 >> 1;                      // row-group (32 rows/half)
  const int nblk = ((bid >> 3) << 1) | (e8 & 1); // bijective 0..63
  const int bn0 = nblk * 64;
  const int fr = lane & 15, fq = lane >> 4;
  const int rowA = mh * 32, rowB = 128 + mh * 32;

  // once-per-launch agent acquire: invalidate stale L2 lines (graph replays)
  if (tid == 0)
    (void)__hip_atomic_load(flags, __ATOMIC_ACQUIRE, __HIP_MEMORY_SCOPE_AGENT);
  __syncthreads();

  const int j = nblk * 16 + fr;
  const float bfv = bf_[j], biv = bi_[j], bgv = bg_[j], bov = bo_[j];
  float crA = 0.f, crB = 0.f;      // 1 cell per thread per half

  // ---- B panel -> registers, once (96 VGPR/lane), shared by both halves
  bf16x8 breg[6][4];
#pragma unroll
  for (int s = 0; s < 6; ++s) {
    const int ks = wid + 8 * s;
#pragma unroll
    for (int nf = 0; nf < 4; ++nf)
      breg[s][nf] = *(const bf16x8*)(Bt + (size_t)(bn0 + nf * 16 + fr) * KTOT
                                     + ks * 32 + fq * 8);
  }

  // A-operand slots (2 frags each): x per half + shared h ladder
  bf16x8 xA0[2], xA1[2], xB0[2], xB1[2], h2[2], h3[2], h4[2], h5[2];

  auto ldx = [&](int t2, int rowbase, int s, bf16x8 (&sl)[2]) {
    const bf16* src = xb + (size_t)t2 * BATCH * DIN + (wid + 8 * s) * 32 + fq * 8;
#pragma unroll
    for (int mf = 0; mf < 2; ++mf)
      sl[mf] = *(const bf16x8*)(src + (size_t)(rowbase + mf * 16 + fr) * DIN);
  };
  auto ldh = [&](int t2, int half, int s, bf16x8 (&sl)[2]) {
    const int c0 = (wid + 8 * s) * 32 - 512;
    const int pp = (c0 >> 4) + (fq >> 1);
    const bf16* base = (t2 == 0)
        ? zb16
        : hseq + ((((size_t)(t2 - 1) * 2 + half) << 8) + mh * 64 + pp) * 512;
    const int coloff = (fq & 1) * 8;
#pragma unroll
    for (int mf = 0; mf < 2; ++mf)
      sl[mf] = *(const bf16x8*)(base + (mf * 16 + fr) * 16 + coloff);
  };

  // per-wave poll of this wave's 8 h-producers (same (half, mh) group)
  const int pn8 = 2 * wid + ((lane & 7) >> 1) * 16 + (lane & 1);
  auto pollh = [&](int tprev, int half) {
    const unsigned* f = flags + (((size_t)tprev * 2 + half) << 8) + mh * 64 + pn8;
    const unsigned long long tt0 = __builtin_amdgcn_s_memrealtime();
    for (;;) {
      unsigned v = __hip_atomic_load(f, __ATOMIC_RELAXED,
                                     __HIP_MEMORY_SCOPE_AGENT);
      if (__all(v != 0)) break;
      __builtin_amdgcn_s_sleep(1);
      if (__builtin_amdgcn_s_memrealtime() - tt0 > (1ULL << 22)) break;  // fail-soft
    }
    asm volatile("" ::: "memory");
    __builtin_amdgcn_sched_barrier(0);
  };

  auto dump = [&](f32x4 (&acc)[2][4]) {
#pragma unroll
    for (int mf = 0; mf < 2; ++mf)
#pragma unroll
      for (int nf = 0; nf < 4; ++nf)
        redu[wid][mf * 4 + nf][lane] = acc[mf][nf];
  };

  // owner cell: row = wid*4+fq (of 32), col j. frag mf=wid>>2,
  // lane_sel=(wid&3)*16+fr, reg=fq  (C/D: col=lane&15, row=(lane>>4)*4+reg)
  auto finish = [&](int t2, int half, float& cre) {
    const int mf_c = wid >> 2;
    const int lsel = (wid & 3) * 16 + fr;
    float z[4];
#pragma unroll
    for (int nf = 0; nf < 4; ++nf) {
      float s_ = 0.f;
#pragma unroll
      for (int s = 0; s < 8; ++s)
        s_ += ((const float*)&redu[s][mf_c * 4 + nf][lsel])[fq];
      z[nf] = s_;
    }
    const float fg = fsigmoid(z[0] + bfv);
    const float ig = fsigmoid(z[1] + biv);
    const float gg = ftanh(z[2] + bgv);
    const float og = fsigmoid(z[3] + bov);
    cre = fg * cre + ig * gg;
    const float h = og * ftanh(cre);
    // hseq tile store: one full 128B line per wave
    bf16* tile = hseq + ((((size_t)t2 * 2 + half) << 8) + mh * 64 + nblk) * 512;
    store_bf16_sc(&tile[wid * 64 + lane], (bf16)h);
    const int rowg = half * 128 + mh * 32 + wid * 4 + fq;
    outF[(size_t)t2 * BHSZ + (size_t)rowg * HID + j] = h;
    if (t2 == T_STEPS - 1)
      outF[(size_t)(T_STEPS + 1) * BHSZ + (size_t)rowg * HID + j] = cre;
  };

  auto setflag = [&](int t2, int half) {
    __hip_atomic_store(&flags[(((size_t)t2 * 2 + half) << 8) + mh * 64 + nblk],
                       1u, __ATOMIC_RELAXED, __HIP_MEMORY_SCOPE_AGENT);
  };

#define MFMA8(ACC, SL, S) do {                                              \
    __builtin_amdgcn_s_setprio(1);                                          \
    _Pragma("unroll")                                                       \
    for (int mf_ = 0; mf_ < 2; ++mf_) {                                     \
      _Pragma("unroll")                                                     \
      for (int nf_ = 0; nf_ < 4; ++nf_)                                     \
        ACC[mf_][nf_] = __builtin_amdgcn_mfma_f32_16x16x32_bf16(            \
            SL[mf_], breg[S][nf_], ACC[mf_][nf_], 0, 0, 0);                 \
    }                                                                       \
    __builtin_amdgcn_s_setprio(0);                                          \
  } while (0)

  // prologue: x of step 0 for both halves; xA drained, xB in flight
  ldx(0, rowA, 0, xA0); SBAR(); ldx(0, rowA, 1, xA1); SBAR();
  ldx(0, rowB, 0, xB0); SBAR(); ldx(0, rowB, 1, xB1); SBAR();
  VMW(4);

#pragma unroll 1
  for (int t = 0; t < T_STEPS; ++t) {
    f32x4 accA[2][4] = {}, accB[2][4] = {};
    // ---- half A: x MFMAs, poll, issue h loads
    MFMA8(accA, xA0, 0); MFMA8(accA, xA1, 1);
    if (t > 0) pollh(t - 1, 0);
    ldh(t, 0, 2, h2); SBAR(); ldh(t, 0, 3, h3); SBAR();
    ldh(t, 0, 4, h4); SBAR(); ldh(t, 0, 5, h5); SBAR();
    // half B x MFMAs hide A's h RTT (also completes [outB, xB'] leftovers)
    VMW(8);
    MFMA8(accB, xB0, 0); MFMA8(accB, xB1, 1);
    // half A h MFMAs, counted ladder
    VMW(6); MFMA8(accA, h2, 2);
    VMW(4); MFMA8(accA, h3, 3);
    VMW(2); MFMA8(accA, h4, 4);
    VMW(0); MFMA8(accA, h5, 5);
    dump(accA); LGKM0(); RAWBAR();
    // ---- half B: poll + issue h loads; A's reduce/epilogue hides B's RTT
    if (t > 0) pollh(t - 1, 1);
    ldh(t, 1, 2, h2); SBAR(); ldh(t, 1, 3, h3); SBAR();
    ldh(t, 1, 4, h4); SBAR(); ldh(t, 1, 5, h5); SBAR();
    finish(t, 0, crA);                       // + hseqA, outA stores
    if (t + 1 < T_STEPS) {
      ldx(t + 1, rowA, 0, xA0); SBAR(); ldx(t + 1, rowA, 1, xA1); SBAR();
      // Q=[hB8, stA, outA, xA4]: ack stA (and hB) -> leave [outA, xA4]
      VMW(5);
    } else {
      VMW(0);
    }
    RAWBAR();
    if (tid == 0) setflag(t, 0);
    // ---- half B h MFMAs (all landed), dump, finish
    MFMA8(accB, h2, 2); MFMA8(accB, h3, 3);
    MFMA8(accB, h4, 4); MFMA8(accB, h5, 5);
    dump(accB); LGKM0(); RAWBAR();
    finish(t, 1, crB);                       // + hseqB, outB stores
    if (t + 1 < T_STEPS) {
      ldx(t + 1, rowB, 0, xB0); SBAR(); ldx(t + 1, rowB, 1, xB1); SBAR();
      // Q=[outA, xA4, stB, outB, xB4]: ack stB -> leave [outB, xB4]
      VMW(4);
    } else {
      VMW(0);
    }
    RAWBAR();
    if (tid == 0) setflag(t, 1);
  }
#undef MFMA8
}

// ---------------------------------------------------------------------------
// Fallback (small ws): round-5 MODE-1 path verbatim (fp32 A from X / out).
__global__ __launch_bounds__(512, 2)
void lstm_fb(const bf16* __restrict__ Bt,
             const float* __restrict__ X,
             const float* __restrict__ zbF,
             float* __restrict__ outF,
             const float* __restrict__ bf_, const float* __restrict__ bi_,
             const float* __restrict__ bg_, const float* __restrict__ bo_,
             unsigned* __restrict__ flags) {
  __shared__ f32x4 redu[8][16][64];
  const int tid = threadIdx.x, lane = tid & 63, wid = tid >> 6;
  const int bid = blockIdx.x;
  const int xcd = bid & 7, sl = bid >> 3;
  const int nblk = xcd * 8 + (sl & 7);
  const int mblk = sl >> 3;
  const int bm0 = mblk * 64;
  const int bn0 = nblk * 64;
  const int fr = lane & 15, fq = lane >> 4;

  if (tid == 0)
    (void)__hip_atomic_load(flags, __ATOMIC_ACQUIRE, __HIP_MEMORY_SCOPE_AGENT);
  __syncthreads();

  const int j = nblk * 16 + fr;
  const float bfv = bf_[j], biv = bi_[j], bgv = bg_[j], bov = bo_[j];
  float cr[2] = {0.f, 0.f};

  bf16x8 breg[6][4];
#pragma unroll
  for (int s = 0; s < 6; ++s) {
    const int ks = wid + 8 * s;
#pragma unroll
    for (int nf = 0; nf < 4; ++nf)
      breg[s][nf] = *(const bf16x8*)(Bt + (size_t)(bn0 + nf * 16 + fr) * KTOT
                                     + ks * 32 + fq * 8);
  }

  bf16x8 afp[2][4];

  auto poll = [&](int tprev) {
    const unsigned* f = flags + (size_t)tprev * 256 + mblk * 64;
    const unsigned long long tt0 = __builtin_amdgcn_s_memrealtime();
    for (;;) {
      unsigned v = __hip_atomic_load(f + lane, __ATOMIC_RELAXED,
                                     __HIP_MEMORY_SCOPE_AGENT);
      if (__all(v != 0)) break;
      __builtin_amdgcn_s_sleep(2);
      if (__builtin_amdgcn_s_memrealtime() - tt0 > (1ULL << 22)) break;
    }
    asm volatile("" ::: "memory");
    __builtin_amdgcn_sched_barrier(0);
  };

  auto loadA = [&](int t2, int s, int p) __attribute__((always_inline)) {
    const int ks = wid + 8 * s;
    const int k = ks * 32 + fq * 8;
    if (s == 2 && t2 > 0) poll(t2 - 1);
    const float* src; int ld, kk;
    if (s < 2) { src = X + (size_t)t2 * BATCH * DIN; ld = DIN; kk = k; }
    else {
      src = (t2 == 0) ? zbF : outF + (size_t)(t2 - 1) * BHSZ;
      ld = HID; kk = k - 512;
    }
#pragma unroll
    for (int mf = 0; mf < 4; ++mf) {
      const float* q = src + (size_t)(bm0 + mf * 16 + fr) * ld + kk;
      const f32x4 lo = *(const f32x4*)q;
      const f32x4 hi = *(const f32x4*)(q + 4);
      bf16x8 v;
      v[0] = (bf16)lo[0]; v[1] = (bf16)lo[1]; v[2] = (bf16)lo[2]; v[3] = (bf16)lo[3];
      v[4] = (bf16)hi[0]; v[5] = (bf16)hi[1]; v[6] = (bf16)hi[2]; v[7] = (bf16)hi[3];
      afp[p][mf] = v;
    }
  };

  loadA(0, 0, 0);

#pragma unroll 1
  for (int t = 0; t < T_STEPS; ++t) {
    f32x4 acc[4][4] = {};
#pragma unroll
    for (int s = 0; s < 6; ++s) {
      if (s < 5)                loadA(t, s + 1, (s + 1) & 1);
      else if (t + 1 < T_STEPS) loadA(t + 1, 0, 0);
      __builtin_amdgcn_s_setprio(1);
#pragma unroll
      for (int mf = 0; mf < 4; ++mf)
#pragma unroll
        for (int nf = 0; nf < 4; ++nf)
          acc[mf][nf] = __builtin_amdgcn_mfma_f32_16x16x32_bf16(
              afp[s & 1][mf], breg[s][nf], acc[mf][nf], 0, 0, 0);
      __builtin_amdgcn_s_setprio(0);
    }

#pragma unroll
    for (int mf = 0; mf < 4; ++mf)
#pragma unroll
      for (int nf = 0; nf < 4; ++nf)
        redu[wid][mf * 4 + nf][lane] = acc[mf][nf];
    __syncthreads();

    const int fbase = (wid >> 1) * 4;
    const int rh = wid & 1;
    float z[2][4];
#pragma unroll
    for (int e = 0; e < 2; ++e) {
      const int rloc = rh * 8 + fq * 2 + e;
      const int lsel = (rloc >> 2) * 16 + fr;
      const int rc = rloc & 3;
#pragma unroll
      for (int nf = 0; nf < 4; ++nf) {
        float sum = 0.f;
#pragma unroll
        for (int s = 0; s < 8; ++s)
          sum += ((const float*)&redu[s][fbase + nf][lsel])[rc];
        z[e][nf] = sum;
      }
    }

    float* outSl = outF + (size_t)t * BHSZ;
#pragma unroll
    for (int e = 0; e < 2; ++e) {
      const float fg = 1.f / (1.f + expf(-(z[e][0] + bfv)));
      const float ig = 1.f / (1.f + expf(-(z[e][1] + biv)));
      const float gg = tanhf(z[e][2] + bgv);
      const float og = 1.f / (1.f + expf(-(z[e][3] + bov)));
      cr[e] = fg * cr[e] + ig * gg;
      const float h = og * tanhf(cr[e]);
      const int m = bm0 + wid * 8 + fq * 2 + e;
      const size_t off = (size_t)m * HID + j;
      __hip_atomic_store(&outSl[off], h, __ATOMIC_RELAXED,
                         __HIP_MEMORY_SCOPE_AGENT);
      if (t == T_STEPS - 1)
        outF[(size_t)(T_STEPS + 1) * BHSZ + off] = cr[e];
    }
    asm volatile("s_waitcnt vmcnt(0)" ::: "memory");
    __syncthreads();
    if (tid == 0)
      __hip_atomic_store(&flags[(size_t)t * 256 + mblk * 64 + nblk], 1u,
                         __ATOMIC_RELAXED, __HIP_MEMORY_SCOPE_AGENT);
  }
}

// ---------------------------------------------------------------------------
extern "C" void kernel_launch(void* const* d_in, const int* in_sizes, int n_in,
                              void* d_out, int out_size, void* d_ws, size_t ws_size,
                              hipStream_t stream) {
  const float* X   = (const float*)d_in[0];
  const float* Wf  = (const float*)d_in[1];
  const float* bf_ = (const float*)d_in[2];
  const float* Wi  = (const float*)d_in[3];
  const float* bi_ = (const float*)d_in[4];
  const float* Wg  = (const float*)d_in[5];
  const float* bg_ = (const float*)d_in[6];
  const float* Wo  = (const float*)d_in[7];
  const float* bo_ = (const float*)d_in[8];
  float* out = (float*)d_out;

  const size_t WtB   = (size_t)NOUT * KTOT * 2;            // 12.58 MB
  const size_t zBb   = BHSZ * 4;                           // 1 MB zeros
  const size_t flagB = (size_t)T_STEPS * 2 * 256 * 4;      // 512 KB
  const size_t XbB   = (size_t)T_STEPS * BATCH * DIN * 2;  // 67.1 MB
  const size_t HsB   = (size_t)T_STEPS * 2 * 256 * 1024;   // 134.2 MB (tiled)

  char* ws = (char*)d_ws;
  bf16*     Wt    = (bf16*)ws;              ws += WtB;
  float*    zbF   = (float*)(void*)ws;      ws += zBb;
  unsigned* flags = (unsigned*)(void*)ws;   ws += flagB;

  const bool big = ws_size >= WtB + zBb + flagB + XbB + HsB + (1u << 20);
  bf16* xbp = nullptr;  bf16* hseq = nullptr;
  if (big) {
    xbp  = (bf16*)ws;   ws += XbB;
    hseq = (bf16*)ws;
  }

  // zeros + flags (re-zeroed every launch -> deterministic)
  hipMemsetAsync(zbF, 0, zBb + flagB, stream);

  convert_w_kernel<<<dim3(KTOT / 64, NOUT / 64), 256, 0, stream>>>(Wf, Wi, Wg, Wo, Wt);

  if (big) {
    convert_x_kernel<<<dim3(BATCH * DIN / 4 / 256, T_STEPS), 256, 0, stream>>>(X, xbp);
    lstm_v13<<<256, 512, 0, stream>>>(Wt, xbp, hseq, (const bf16*)zbF, out,
                                      bf_, bi_, bg_, bo_, flags);
  } else {
    lstm_fb<<<256, 512, 0, stream>>>(Wt, X, zbF, out,
                                     bf_, bi_, bg_, bo_, flags);
  }

  // hx = outputs[T-1] (cx stored by the kernel)
  hipMemcpyAsync(out + (size_t)T_STEPS * BHSZ, out + (size_t)(T_STEPS - 1) * BHSZ,
                 BHSZ * 4, hipMemcpyDeviceToDevice, stream);
}